// Round 2
// baseline (196.357 us; speedup 1.0000x reference)
//
#include <hip/hip_runtime.h>

#define NPTS  1048576
#define BLOCK 256
#define PPB   128           // points per block (2 threads per point)
#define D     16
#define ROW   35            // 3 coords + 2*16 emb dims
#define CHUNK (PPB * ROW)   // floats per block in output (4480)

#define N0 (5 * 91 * 161 * 16)   // 1172080 bytes in fp8
#define N1 (3 * 46 * 81 * 16)    //  178848
#define T8 ((N0 + N1) / 8)       // 168866 threads for cvt

#define SCALE   4096.0f
#define UNSCALE (1.0f / 4096.0f)

typedef float vf2 __attribute__((ext_vector_type(2)));
typedef float vf4 __attribute__((ext_vector_type(4)));

// ---- table conversion: f32 -> fp8 e4m3 (scaled) into workspace ----
__global__ __launch_bounds__(256) void cvt_kernel(const float* __restrict__ e0,
                                                  const float* __restrict__ e1,
                                                  unsigned char* __restrict__ dst) {
    int i = blockIdx.x * 256 + threadIdx.x;
    if (i >= T8) return;
    int e = i * 8;
    const float* src = (e < N0) ? (e0 + e) : (e1 + (e - N0));
    float4 a = *(const float4*)(src);
    float4 b = *(const float4*)(src + 4);
    int w0 = __builtin_amdgcn_cvt_pk_fp8_f32(a.x * SCALE, a.y * SCALE, 0, false);
    w0     = __builtin_amdgcn_cvt_pk_fp8_f32(a.z * SCALE, a.w * SCALE, w0, true);
    int w1 = __builtin_amdgcn_cvt_pk_fp8_f32(b.x * SCALE, b.y * SCALE, 0, false);
    w1     = __builtin_amdgcn_cvt_pk_fp8_f32(b.z * SCALE, b.w * SCALE, w1, true);
    uint2 packed;
    packed.x = (unsigned int)w0;
    packed.y = (unsigned int)w1;
    *reinterpret_cast<uint2*>(dst + e) = packed;
}

// lane-pair swap (lanes 2p <-> 2p+1) via DPP quad_perm:[1,0,3,2] — 1 VALU op
__device__ __forceinline__ unsigned swap1(unsigned v) {
    return (unsigned)__builtin_amdgcn_update_dpp(0, (int)v, 0xB1, 0xF, 0xF, true);
}

// Per level: 4 (t,u) row combos. Each lane loads the FULL 16B cell (iw0 + h);
// channel-halves are exchanged between the lane pair afterwards.
// Inputs are in [0,1): ct < GT-1 etc., so corner+1 never clamps (lower clamps
// are no-ops too). iw0 <= GW-2 guaranteed; min() kept purely as an OOB guard.
template <int GT, int GU, int GW>
__device__ __forceinline__ void prep2(float x, float y, float z, int h,
                                      int* __restrict__ cb,     // [4] cell byte offsets
                                      float* __restrict__ wtu,  // [4] wt*wu
                                      float& wwn, float& wwf) { // own/far w-weights
    float ct = x * (float)(GT - 1);
    float cu = y * (float)(GU - 1);
    float cw = z * (float)(GW - 1);

    float t0 = floorf(ct), u0 = floorf(cu), w0 = floorf(cw);
    float t1 = fminf(t0 + 1.f, (float)(GT - 1));
    float u1 = fminf(u0 + 1.f, (float)(GU - 1));
    float w1 = fminf(w0 + 1.f, (float)(GW - 1));

    float wt[2] = {1.f - fabsf(t0 - ct), 1.f - fabsf(t1 - ct)};
    float wu[2] = {1.f - fabsf(u0 - cu), 1.f - fabsf(u1 - cu)};
    float ww0   = 1.f - fabsf(w0 - cw);
    float ww1   = 1.f - fabsf(w1 - cw);
    int   it[2] = {(int)t0, (int)t1};
    int   iu[2] = {(int)u0, (int)u1};
    int   iw0   = min((int)w0, GW - 2);

#pragma unroll
    for (int a = 0; a < 2; ++a)
#pragma unroll
        for (int b = 0; b < 2; ++b) {
            int k  = a * 2 + b;
            cb[k]  = ((it[a] * GU + iu[b]) * GW + iw0 + h) * D;  // bytes (1 B/elem)
            wtu[k] = wt[a] * wu[b];
        }
    wwn = h ? ww1 : ww0;   // weight of MY loaded cell (iw0+h)
    wwf = h ? ww0 : ww1;   // weight of the partner's cell
}

// accumulate 8 fp8 channels (two dwords) with weight w into acc[0..8)
__device__ __forceinline__ void accum8w(unsigned d0, unsigned d1, float w,
                                        float* __restrict__ acc) {
    vf2 f01 = __builtin_amdgcn_cvt_pk_f32_fp8((int)d0, false);
    vf2 f23 = __builtin_amdgcn_cvt_pk_f32_fp8((int)d0, true);
    vf2 f45 = __builtin_amdgcn_cvt_pk_f32_fp8((int)d1, false);
    vf2 f67 = __builtin_amdgcn_cvt_pk_f32_fp8((int)d1, true);
    acc[0] = fmaf(w, f01.x, acc[0]);
    acc[1] = fmaf(w, f01.y, acc[1]);
    acc[2] = fmaf(w, f23.x, acc[2]);
    acc[3] = fmaf(w, f23.y, acc[3]);
    acc[4] = fmaf(w, f45.x, acc[4]);
    acc[5] = fmaf(w, f45.y, acc[5]);
    acc[6] = fmaf(w, f67.x, acc[6]);
    acc[7] = fmaf(w, f67.y, acc[7]);
}

// process one level's 4 combos: DPP-exchange halves, accumulate own+far cells
__device__ __forceinline__ void process4(const uint4* __restrict__ v,
                                         const float* __restrict__ wtu,
                                         float wwn, float wwf, int h,
                                         float* __restrict__ acc) {
#pragma unroll
    for (int k = 0; k < 4; ++k) {
        unsigned sx = swap1(v[k].x), sy = swap1(v[k].y);
        unsigned sz = swap1(v[k].z), sw = swap1(v[k].w);
        unsigned o0 = h ? v[k].z : v[k].x;   // my cell, my channel-half
        unsigned o1 = h ? v[k].w : v[k].y;
        unsigned f0 = h ? sz : sx;           // partner cell, my channel-half
        unsigned f1 = h ? sw : sy;
        accum8w(o0, o1, wtu[k] * wwn, acc);
        accum8w(f0, f1, wtu[k] * wwf, acc);
    }
}

__global__ __launch_bounds__(BLOCK) void mhe_kernel(
    const float* __restrict__ in,            // [N,3]
    const unsigned char* __restrict__ e0,    // [5,91,161,16] fp8 e4m3 (x4096)
    const unsigned char* __restrict__ e1,    // [3,46,81,16]  fp8 e4m3 (x4096)
    float* __restrict__ out)                 // [N,35]
{
    __shared__ float sin_[PPB * 3];   // 1536 B
    __shared__ float sout[CHUNK];     // 17920 B

    const int tid  = threadIdx.x;
    const int base = blockIdx.x * PPB;

    // coalesced input staging: 384 floats as 192 2-float vectors (nt: no reuse)
    if (tid < PPB * 3 / 2) {
        reinterpret_cast<vf2*>(sin_)[tid] = __builtin_nontemporal_load(
            reinterpret_cast<const vf2*>(in + (size_t)base * 3) + tid);
    }
    __syncthreads();

    const int p = tid >> 1;     // point within block
    const int h = tid & 1;      // channel half (8 channels)

    float x = sin_[p * 3 + 0];
    float y = sin_[p * 3 + 1];
    float z = sin_[p * 3 + 2];

    int   cb0[4], cb1[4];
    float wtu0[4], wtu1[4];
    float wwn0, wwf0, wwn1, wwf1;
    prep2<5, 91, 161>(x, y, z, h, cb0, wtu0, wwn0, wwf0);
    prep2<3, 46, 81>(x, y, z, h, cb1, wtu1, wwn1, wwf1);

    // issue all 8 independent 16B gathers before any accumulation (max MLP);
    // lane pair (2p,2p+1) covers a contiguous 32B span -> one line-request ~75%
    uint4 v0[4], v1[4];
#pragma unroll
    for (int k = 0; k < 4; ++k) v0[k] = *reinterpret_cast<const uint4*>(e0 + cb0[k]);
#pragma unroll
    for (int k = 0; k < 4; ++k) v1[k] = *reinterpret_cast<const uint4*>(e1 + cb1[k]);

    float a0[8] = {0,0,0,0,0,0,0,0};
    float a1[8] = {0,0,0,0,0,0,0,0};
    process4(v0, wtu0, wwn0, wwf0, h, a0);
    process4(v1, wtu1, wwn1, wwf1, h, a1);

    float* row = sout + p * ROW;
    if (h == 0) { row[0] = x; row[1] = y; row[2] = z; }
#pragma unroll
    for (int k = 0; k < 8; ++k) {
        row[3 + h * 8 + k]     = a0[k] * UNSCALE;
        row[3 + D + h * 8 + k] = a1[k] * UNSCALE;
    }
    __syncthreads();

    // coalesced flush: 1120 16B stores per block; nontemporal so the 140 MB
    // out-stream doesn't evict the 1.35 MB table from the per-XCD L2
    vf4*       ob = reinterpret_cast<vf4*>(out + (size_t)blockIdx.x * CHUNK);
    const vf4* lb = reinterpret_cast<const vf4*>(sout);
    for (int i = tid; i < CHUNK / 4; i += BLOCK) {
        __builtin_nontemporal_store(lb[i], ob + i);
    }
}

extern "C" void kernel_launch(void* const* d_in, const int* in_sizes, int n_in,
                              void* d_out, int out_size, void* d_ws, size_t ws_size,
                              hipStream_t stream) {
    const float* in   = (const float*)d_in[0];
    const float* emb0 = (const float*)d_in[1];
    const float* emb1 = (const float*)d_in[2];
    float*       out  = (float*)d_out;

    unsigned char* tbl = (unsigned char*)d_ws;   // e0 at [0, N0), e1 at [N0, N0+N1)

    cvt_kernel<<<(T8 + 255) / 256, 256, 0, stream>>>(emb0, emb1, tbl);
    mhe_kernel<<<NPTS / PPB, BLOCK, 0, stream>>>(in, tbl, tbl + N0, out);
}

// Round 4
// 194.829 us; speedup vs baseline: 1.0078x; 1.0078x over previous
//
#include <hip/hip_runtime.h>

#define NPTS  1048576
#define BLOCK 256
#define PPB   128           // points per block (2 threads per point)
#define D     16
#define ROW   35            // 3 coords + 2*16 emb dims
#define CHUNK (PPB * ROW)   // floats per block in output (4480)

#define N0 (5 * 91 * 161 * 16)   // 1172080 bytes in fp8
#define N1 (3 * 46 * 81 * 16)    //  178848
#define T8 ((N0 + N1) / 8)       // 168866 threads for cvt

#define SCALE   4096.0f
#define UNSCALE (1.0f / 4096.0f)

typedef float vf2 __attribute__((ext_vector_type(2)));

// ---- table conversion: f32 -> fp8 e4m3 (scaled) into workspace ----
__global__ __launch_bounds__(256) void cvt_kernel(const float* __restrict__ e0,
                                                  const float* __restrict__ e1,
                                                  unsigned char* __restrict__ dst) {
    int i = blockIdx.x * 256 + threadIdx.x;
    if (i >= T8) return;
    int e = i * 8;
    const float* src = (e < N0) ? (e0 + e) : (e1 + (e - N0));
    float4 a = *(const float4*)(src);
    float4 b = *(const float4*)(src + 4);
    int w0 = __builtin_amdgcn_cvt_pk_fp8_f32(a.x * SCALE, a.y * SCALE, 0, false);
    w0     = __builtin_amdgcn_cvt_pk_fp8_f32(a.z * SCALE, a.w * SCALE, w0, true);
    int w1 = __builtin_amdgcn_cvt_pk_fp8_f32(b.x * SCALE, b.y * SCALE, 0, false);
    w1     = __builtin_amdgcn_cvt_pk_fp8_f32(b.z * SCALE, b.w * SCALE, w1, true);
    uint2 packed;
    packed.x = (unsigned int)w0;
    packed.y = (unsigned int)w1;
    *reinterpret_cast<uint2*>(dst + e) = packed;
}

// lane-pair swap (lanes 2p <-> 2p+1) via DPP quad_perm:[1,0,3,2] — 1 VALU op
__device__ __forceinline__ unsigned swap1(unsigned v) {
    return (unsigned)__builtin_amdgcn_update_dpp(0, (int)v, 0xB1, 0xF, 0xF, true);
}

// Per level: 4 (t,u) row combos; lane h loads the FULL 16B cell (iw0 + h);
// channel-halves are exchanged between the lane pair afterwards.
// REFERENCE-EXACT corners/weights: the reference computes the +1 corner as
// floorf(c + 1.0f) (fp32 add BEFORE floor, then clip). At fp edge cases this
// lands at floor(c)+2 with weight ~-1e-7 (and the weight~1 corner vanishes).
// t/u corners are load indices -> replicate exactly. The w-axis uses the
// reference WEIGHT formula but loads the contiguous pair {iw0, iw0+1}; at the
// freak points the ~-1e-7 weight multiplies the adjacent cell instead of
// floor+2 -> error ~1e-11 (vs ~1e-4 if weights were "algebraically correct").
template <int GT, int GU, int GW>
__device__ __forceinline__ void prep2(float x, float y, float z, int h,
                                      int* __restrict__ cb,     // [4] cell byte offsets
                                      float* __restrict__ wtu,  // [4] wt*wu
                                      float& wwn, float& wwf) { // own/far w-weights
    float ct = x * (float)(GT - 1);
    float cu = y * (float)(GU - 1);
    float cw = z * (float)(GW - 1);

    float t0 = floorf(ct), u0 = floorf(cu), w0 = floorf(cw);
    float t1 = fminf(floorf(ct + 1.f), (float)(GT - 1));
    float u1 = fminf(floorf(cu + 1.f), (float)(GU - 1));
    float w1 = fminf(floorf(cw + 1.f), (float)(GW - 1));

    float wt[2] = {1.f - fabsf(t0 - ct), 1.f - fabsf(t1 - ct)};
    float wu[2] = {1.f - fabsf(u0 - cu), 1.f - fabsf(u1 - cu)};
    float ww0   = 1.f - fabsf(w0 - cw);
    float ww1   = 1.f - fabsf(w1 - cw);
    int   it[2] = {(int)t0, (int)t1};
    int   iu[2] = {(int)u0, (int)u1};
    int   iw0   = min((int)w0, GW - 2);   // provably <= GW-2 for z in [0,1); guard only

#pragma unroll
    for (int a = 0; a < 2; ++a)
#pragma unroll
        for (int b = 0; b < 2; ++b) {
            int k  = a * 2 + b;
            cb[k]  = ((it[a] * GU + iu[b]) * GW + iw0 + h) * D;  // byte offset (1 B/elem)
            wtu[k] = wt[a] * wu[b];
        }
    wwn = h ? ww1 : ww0;   // weight of MY loaded cell (iw0+h)
    wwf = h ? ww0 : ww1;   // weight of the partner's cell
}

// accumulate 8 fp8 channels (two dwords) with weight w into acc[0..8)
__device__ __forceinline__ void accum8w(unsigned d0, unsigned d1, float w,
                                        float* __restrict__ acc) {
    vf2 f01 = __builtin_amdgcn_cvt_pk_f32_fp8((int)d0, false);
    vf2 f23 = __builtin_amdgcn_cvt_pk_f32_fp8((int)d0, true);
    vf2 f45 = __builtin_amdgcn_cvt_pk_f32_fp8((int)d1, false);
    vf2 f67 = __builtin_amdgcn_cvt_pk_f32_fp8((int)d1, true);
    acc[0] = fmaf(w, f01.x, acc[0]);
    acc[1] = fmaf(w, f01.y, acc[1]);
    acc[2] = fmaf(w, f23.x, acc[2]);
    acc[3] = fmaf(w, f23.y, acc[3]);
    acc[4] = fmaf(w, f45.x, acc[4]);
    acc[5] = fmaf(w, f45.y, acc[5]);
    acc[6] = fmaf(w, f67.x, acc[6]);
    acc[7] = fmaf(w, f67.y, acc[7]);
}

// process one level's 4 combos: DPP-exchange halves, accumulate own+far cells
__device__ __forceinline__ void process4(const uint4* __restrict__ v,
                                         const float* __restrict__ wtu,
                                         float wwn, float wwf, int h,
                                         float* __restrict__ acc) {
#pragma unroll
    for (int k = 0; k < 4; ++k) {
        unsigned sx = swap1(v[k].x), sy = swap1(v[k].y);
        unsigned sz = swap1(v[k].z), sw = swap1(v[k].w);
        unsigned o0 = h ? v[k].z : v[k].x;   // my cell, my channel-half
        unsigned o1 = h ? v[k].w : v[k].y;
        unsigned f0 = h ? sz : sx;           // partner cell, my channel-half
        unsigned f1 = h ? sw : sy;
        accum8w(o0, o1, wtu[k] * wwn, acc);
        accum8w(f0, f1, wtu[k] * wwf, acc);
    }
}

__global__ __launch_bounds__(BLOCK) void mhe_kernel(
    const float* __restrict__ in,            // [N,3]
    const unsigned char* __restrict__ e0,    // [5,91,161,16] fp8 e4m3 (x4096)
    const unsigned char* __restrict__ e1,    // [3,46,81,16]  fp8 e4m3 (x4096)
    float* __restrict__ out)                 // [N,35]
{
    __shared__ float sin_[PPB * 3];   // 1536 B
    __shared__ float sout[CHUNK];     // 17920 B

    const int tid  = threadIdx.x;
    const int base = blockIdx.x * PPB;

    // coalesced input staging: 384 floats as 192 float2
    if (tid < PPB * 3 / 2) {
        reinterpret_cast<float2*>(sin_)[tid] =
            reinterpret_cast<const float2*>(in + (size_t)base * 3)[tid];
    }
    __syncthreads();

    const int p = tid >> 1;     // point within block
    const int h = tid & 1;      // channel half (8 channels)

    float x = sin_[p * 3 + 0];
    float y = sin_[p * 3 + 1];
    float z = sin_[p * 3 + 2];

    int   cb0[4], cb1[4];
    float wtu0[4], wtu1[4];
    float wwn0, wwf0, wwn1, wwf1;
    prep2<5, 91, 161>(x, y, z, h, cb0, wtu0, wwn0, wwf0);
    prep2<3, 46, 81>(x, y, z, h, cb1, wtu1, wwn1, wwf1);

    // issue all 8 independent 16B gathers before any accumulation (max MLP);
    // lane pair (2p,2p+1) covers a contiguous 32B span -> ~half the line-requests
    uint4 v0[4], v1[4];
#pragma unroll
    for (int k = 0; k < 4; ++k) v0[k] = *reinterpret_cast<const uint4*>(e0 + cb0[k]);
#pragma unroll
    for (int k = 0; k < 4; ++k) v1[k] = *reinterpret_cast<const uint4*>(e1 + cb1[k]);

    float a0[8] = {0,0,0,0,0,0,0,0};
    float a1[8] = {0,0,0,0,0,0,0,0};
    process4(v0, wtu0, wwn0, wwf0, h, a0);
    process4(v1, wtu1, wwn1, wwf1, h, a1);

    float* row = sout + p * ROW;
    if (h == 0) { row[0] = x; row[1] = y; row[2] = z; }
#pragma unroll
    for (int k = 0; k < 8; ++k) {
        row[3 + h * 8 + k]     = a0[k] * UNSCALE;
        row[3 + D + h * 8 + k] = a1[k] * UNSCALE;
    }
    __syncthreads();

    // coalesced flush: 1120 float4 per block (plain stores — nt regressed)
    float4*       ob = reinterpret_cast<float4*>(out + (size_t)blockIdx.x * CHUNK);
    const float4* lb = reinterpret_cast<const float4*>(sout);
    for (int i = tid; i < CHUNK / 4; i += BLOCK) {
        ob[i] = lb[i];
    }
}

extern "C" void kernel_launch(void* const* d_in, const int* in_sizes, int n_in,
                              void* d_out, int out_size, void* d_ws, size_t ws_size,
                              hipStream_t stream) {
    const float* in   = (const float*)d_in[0];
    const float* emb0 = (const float*)d_in[1];
    const float* emb1 = (const float*)d_in[2];
    float*       out  = (float*)d_out;

    unsigned char* tbl = (unsigned char*)d_ws;   // e0 at [0, N0), e1 at [N0, N0+N1)

    cvt_kernel<<<(T8 + 255) / 256, 256, 0, stream>>>(emb0, emb1, tbl);
    mhe_kernel<<<NPTS / PPB, BLOCK, 0, stream>>>(in, tbl, tbl + N0, out);
}

// Round 5
// 188.151 us; speedup vs baseline: 1.0436x; 1.0355x over previous
//
#include <hip/hip_runtime.h>

#define NPTS  1048576
#define BLOCK 256
#define PPB   128           // points per block (2 threads per point)
#define D     16
#define ROW   35            // 3 coords + 2*16 emb dims
#define CHUNK (PPB * ROW)   // floats per block in output (4480)

#define N0 (5 * 91 * 161 * 16)   // 1172080 bytes in fp8 (vertex table, fallback)
#define N1 (3 * 46 * 81 * 16)    //  178848
#define T8 ((N0 + N1) / 8)       // 168866 threads for fallback cvt

// duplicated-corner cell tables: 128 B per cell (8 corners x 16 fp8 ch)
#define CELLS0 (4 * 90 * 160)    // 57600
#define CELLS1 (2 * 45 * 80)     //  7200
#define DUPSZ  ((size_t)(CELLS0 + CELLS1) * 128)   // 8294400 B
#define TOT2   ((CELLS0 + CELLS1) * 2)             // threads for cvt2 (cell,half)

#define SCALE   4096.0f
#define UNSCALE (1.0f / 4096.0f)

typedef float vf2 __attribute__((ext_vector_type(2)));

// ======================= NEW PATH: cell-duplicated layout =======================

// expand one cell-half: gather 8 corners' channels [8h..8h+8) from f32 vertex
// table, convert to fp8 e4m3 (x4096), write 64 B contiguous.
template <int GT, int GU, int GW>
__device__ __forceinline__ void expand_cell(const float* __restrict__ src,
                                            int cid, int h,
                                            unsigned char* __restrict__ dst) {
    const int CW = GW - 1, CU = GU - 1;
    int w = cid % CW;
    int r = cid / CW;
    int u = r % CU;
    int t = r / CU;

    uint2 arr[8];
#pragma unroll
    for (int k = 0; k < 8; ++k) {
        int a = (k >> 2) & 1, b = (k >> 1) & 1, c = k & 1;
        const float* s = src + ((size_t)((t + a) * GU + (u + b)) * GW + (w + c)) * D + h * 8;
        float4 lo = *(const float4*)s;
        float4 hi = *(const float4*)(s + 4);
        int d0 = __builtin_amdgcn_cvt_pk_fp8_f32(lo.x * SCALE, lo.y * SCALE, 0, false);
        d0     = __builtin_amdgcn_cvt_pk_fp8_f32(lo.z * SCALE, lo.w * SCALE, d0, true);
        int d1 = __builtin_amdgcn_cvt_pk_fp8_f32(hi.x * SCALE, hi.y * SCALE, 0, false);
        d1     = __builtin_amdgcn_cvt_pk_fp8_f32(hi.z * SCALE, hi.w * SCALE, d1, true);
        arr[k].x = (unsigned)d0;
        arr[k].y = (unsigned)d1;
    }
    uint4* o = (uint4*)(dst + (size_t)cid * 128 + h * 64);
#pragma unroll
    for (int j = 0; j < 4; ++j)
        o[j] = make_uint4(arr[2 * j].x, arr[2 * j].y, arr[2 * j + 1].x, arr[2 * j + 1].y);
}

__global__ __launch_bounds__(256) void cvt2_kernel(const float* __restrict__ e0,
                                                   const float* __restrict__ e1,
                                                   unsigned char* __restrict__ dst) {
    int i = blockIdx.x * 256 + threadIdx.x;
    if (i >= TOT2) return;
    int h   = i & 1;
    int cid = i >> 1;
    if (cid < CELLS0) expand_cell<5, 91, 161>(e0, cid, h, dst);
    else              expand_cell<3, 46, 81>(e1, cid - CELLS0, h, dst + (size_t)CELLS0 * 128);
}

// Per-axis cell index + weights for the cell's two vertices {fc, fc+1},
// replicating ALL reference fp quirks:
//  - reference +1 corner = floorf(c+1.0f) then clip. Freak points (c just below
//    integer I): corner lands at I+1 w/ weight -eps, vertex I gets nothing, and
//    vertex I-1 gets +eps. We fold the -eps onto fc+1=I (error ~eps*|d_emb| ~1e-11).
//  - c == G-1 exactly (possible: x=1-2^-24 rounds up): both ref corners = G-1,
//    each weight 1 -> our cell G-2 gets wA=0, wB=2. Exact.
__device__ __forceinline__ void axisw(float x, float Gm1, float Gm2,
                                      int& ic, float& wA, float& wB) {
    float c  = x * Gm1;
    float f0 = floorf(c);
    float f1 = fminf(floorf(c + 1.f), Gm1);
    float w0 = 1.f - fabsf(f0 - c);
    float w1 = 1.f - fabsf(f1 - c);
    float fc = fminf(f0, Gm2);
    ic = (int)fc;
    bool same = (f0 == fc);
    wA = same ? w0 : 0.f;
    wB = same ? w1 : (w0 + w1);
}

// accumulate 8 fp8 channels (two dwords) with weight w into acc[0..8)
__device__ __forceinline__ void accum8w(unsigned d0, unsigned d1, float w,
                                        float* __restrict__ acc) {
    vf2 f01 = __builtin_amdgcn_cvt_pk_f32_fp8((int)d0, false);
    vf2 f23 = __builtin_amdgcn_cvt_pk_f32_fp8((int)d0, true);
    vf2 f45 = __builtin_amdgcn_cvt_pk_f32_fp8((int)d1, false);
    vf2 f67 = __builtin_amdgcn_cvt_pk_f32_fp8((int)d1, true);
    acc[0] = fmaf(w, f01.x, acc[0]);
    acc[1] = fmaf(w, f01.y, acc[1]);
    acc[2] = fmaf(w, f23.x, acc[2]);
    acc[3] = fmaf(w, f23.y, acc[3]);
    acc[4] = fmaf(w, f45.x, acc[4]);
    acc[5] = fmaf(w, f45.y, acc[5]);
    acc[6] = fmaf(w, f67.x, acc[6]);
    acc[7] = fmaf(w, f67.y, acc[7]);
}

template <int GT, int GU, int GW>
__device__ __forceinline__ void level2(float x, float y, float z, int h,
                                       const unsigned char* __restrict__ tbl,
                                       uint4* __restrict__ q,       // [4] out
                                       float* __restrict__ wab,     // [4] out
                                       float& wwA, float& wwB) {
    int it, iu, iw;
    float wtA, wtB, wuA, wuB;
    axisw(x, (float)(GT - 1), (float)(GT - 2), it, wtA, wtB);
    axisw(y, (float)(GU - 1), (float)(GU - 2), iu, wuA, wuB);
    axisw(z, (float)(GW - 1), (float)(GW - 2), iw, wwA, wwB);
    int cell = (it * (GU - 1) + iu) * (GW - 1) + iw;
    const uint4* bp = (const uint4*)(tbl + (size_t)cell * 128 + (h << 6));
#pragma unroll
    for (int j = 0; j < 4; ++j) q[j] = bp[j];   // one 64B line per thread
    wab[0] = wtA * wuA;
    wab[1] = wtA * wuB;
    wab[2] = wtB * wuA;
    wab[3] = wtB * wuB;
}

__global__ __launch_bounds__(BLOCK) void mhe2_kernel(
    const float* __restrict__ in,            // [N,3]
    const unsigned char* __restrict__ t0,    // [CELLS0][8][16] fp8 cell-dup
    const unsigned char* __restrict__ t1,    // [CELLS1][8][16]
    float* __restrict__ out)                 // [N,35]
{
    __shared__ float sin_[PPB * 3];   // 1536 B
    __shared__ float sout[CHUNK];     // 17920 B

    const int tid  = threadIdx.x;
    const int base = blockIdx.x * PPB;

    if (tid < PPB * 3 / 2) {
        reinterpret_cast<float2*>(sin_)[tid] =
            reinterpret_cast<const float2*>(in + (size_t)base * 3)[tid];
    }
    __syncthreads();

    const int p = tid >> 1;     // point within block
    const int h = tid & 1;      // channel half (8 channels)

    float x = sin_[p * 3 + 0];
    float y = sin_[p * 3 + 1];
    float z = sin_[p * 3 + 2];

    uint4 q0[4], q1[4];
    float wab0[4], wab1[4];
    float wwA0, wwB0, wwA1, wwB1;
    level2<5, 91, 161>(x, y, z, h, t0, q0, wab0, wwA0, wwB0);
    level2<3, 46, 81>(x, y, z, h, t1, q1, wab1, wwA1, wwB1);

    float a0[8] = {0,0,0,0,0,0,0,0};
    float a1[8] = {0,0,0,0,0,0,0,0};
#pragma unroll
    for (int kp = 0; kp < 4; ++kp) {
        accum8w(q0[kp].x, q0[kp].y, wab0[kp] * wwA0, a0);   // corner (a,b,0)
        accum8w(q0[kp].z, q0[kp].w, wab0[kp] * wwB0, a0);   // corner (a,b,1)
    }
#pragma unroll
    for (int kp = 0; kp < 4; ++kp) {
        accum8w(q1[kp].x, q1[kp].y, wab1[kp] * wwA1, a1);
        accum8w(q1[kp].z, q1[kp].w, wab1[kp] * wwB1, a1);
    }

    float* row = sout + p * ROW;
    if (h == 0) { row[0] = x; row[1] = y; row[2] = z; }
#pragma unroll
    for (int k = 0; k < 8; ++k) {
        row[3 + h * 8 + k]     = a0[k] * UNSCALE;
        row[3 + D + h * 8 + k] = a1[k] * UNSCALE;
    }
    __syncthreads();

    float4*       ob = reinterpret_cast<float4*>(out + (size_t)blockIdx.x * CHUNK);
    const float4* lb = reinterpret_cast<const float4*>(sout);
    for (int i = tid; i < CHUNK / 4; i += BLOCK) {
        ob[i] = lb[i];
    }
}

// ======================= FALLBACK: Round-0 proven path =======================

__global__ __launch_bounds__(256) void cvt_kernel(const float* __restrict__ e0,
                                                  const float* __restrict__ e1,
                                                  unsigned char* __restrict__ dst) {
    int i = blockIdx.x * 256 + threadIdx.x;
    if (i >= T8) return;
    int e = i * 8;
    const float* src = (e < N0) ? (e0 + e) : (e1 + (e - N0));
    float4 a = *(const float4*)(src);
    float4 b = *(const float4*)(src + 4);
    int w0 = __builtin_amdgcn_cvt_pk_fp8_f32(a.x * SCALE, a.y * SCALE, 0, false);
    w0     = __builtin_amdgcn_cvt_pk_fp8_f32(a.z * SCALE, a.w * SCALE, w0, true);
    int w1 = __builtin_amdgcn_cvt_pk_fp8_f32(b.x * SCALE, b.y * SCALE, 0, false);
    w1     = __builtin_amdgcn_cvt_pk_fp8_f32(b.z * SCALE, b.w * SCALE, w1, true);
    uint2 packed;
    packed.x = (unsigned int)w0;
    packed.y = (unsigned int)w1;
    *reinterpret_cast<uint2*>(dst + e) = packed;
}

template <int GT, int GH, int GW>
__device__ __forceinline__ void prep(float x, float y, float z, int h,
                                     int* __restrict__ off, float* __restrict__ w) {
    float ct = x * (float)(GT - 1);
    float ch = y * (float)(GH - 1);
    float cw = z * (float)(GW - 1);

    float ft0 = fminf(fmaxf(floorf(ct),       0.f), (float)(GT - 1));
    float ft1 = fminf(fmaxf(floorf(ct + 1.f), 0.f), (float)(GT - 1));
    float fh0 = fminf(fmaxf(floorf(ch),       0.f), (float)(GH - 1));
    float fh1 = fminf(fmaxf(floorf(ch + 1.f), 0.f), (float)(GH - 1));
    float fw0 = fminf(fmaxf(floorf(cw),       0.f), (float)(GW - 1));
    float fw1 = fminf(fmaxf(floorf(cw + 1.f), 0.f), (float)(GW - 1));

    float wt[2] = {1.f - fabsf(ft0 - ct), 1.f - fabsf(ft1 - ct)};
    float wh[2] = {1.f - fabsf(fh0 - ch), 1.f - fabsf(fh1 - ch)};
    float ww[2] = {1.f - fabsf(fw0 - cw), 1.f - fabsf(fw1 - cw)};
    int   it[2] = {(int)ft0, (int)ft1};
    int   ih[2] = {(int)fh0, (int)fh1};
    int   iw[2] = {(int)fw0, (int)fw1};

#pragma unroll
    for (int a = 0; a < 2; ++a)
#pragma unroll
        for (int b = 0; b < 2; ++b) {
            int rowbase = (it[a] * GH + ih[b]) * GW;
            float wab   = wt[a] * wh[b];
#pragma unroll
            for (int c = 0; c < 2; ++c) {
                int k  = a * 4 + b * 2 + c;
                off[k] = (rowbase + iw[c]) * D + h * 8;
                w[k]   = wab * ww[c];
            }
        }
}

__device__ __forceinline__ void accum8(uint2 v, float w, float* __restrict__ acc) {
    vf2 f01 = __builtin_amdgcn_cvt_pk_f32_fp8((int)v.x, false);
    vf2 f23 = __builtin_amdgcn_cvt_pk_f32_fp8((int)v.x, true);
    vf2 f45 = __builtin_amdgcn_cvt_pk_f32_fp8((int)v.y, false);
    vf2 f67 = __builtin_amdgcn_cvt_pk_f32_fp8((int)v.y, true);
    acc[0] = fmaf(w, f01.x, acc[0]);
    acc[1] = fmaf(w, f01.y, acc[1]);
    acc[2] = fmaf(w, f23.x, acc[2]);
    acc[3] = fmaf(w, f23.y, acc[3]);
    acc[4] = fmaf(w, f45.x, acc[4]);
    acc[5] = fmaf(w, f45.y, acc[5]);
    acc[6] = fmaf(w, f67.x, acc[6]);
    acc[7] = fmaf(w, f67.y, acc[7]);
}

__global__ __launch_bounds__(BLOCK) void mhe_kernel(
    const float* __restrict__ in,
    const unsigned char* __restrict__ e0,
    const unsigned char* __restrict__ e1,
    float* __restrict__ out)
{
    __shared__ float sin_[PPB * 3];
    __shared__ float sout[CHUNK];

    const int tid  = threadIdx.x;
    const int base = blockIdx.x * PPB;

    if (tid < PPB * 3 / 2) {
        reinterpret_cast<float2*>(sin_)[tid] =
            reinterpret_cast<const float2*>(in + (size_t)base * 3)[tid];
    }
    __syncthreads();

    const int p = tid >> 1;
    const int h = tid & 1;

    float x = sin_[p * 3 + 0];
    float y = sin_[p * 3 + 1];
    float z = sin_[p * 3 + 2];

    int   off0[8], off1[8];
    float w0[8],   w1[8];
    prep<5, 91, 161>(x, y, z, h, off0, w0);
    prep<3, 46, 81>(x, y, z, h, off1, w1);

    uint2 v0[8], v1[8];
#pragma unroll
    for (int k = 0; k < 8; ++k) v0[k] = *reinterpret_cast<const uint2*>(e0 + off0[k]);
#pragma unroll
    for (int k = 0; k < 8; ++k) v1[k] = *reinterpret_cast<const uint2*>(e1 + off1[k]);

    float a0[8] = {0,0,0,0,0,0,0,0};
    float a1[8] = {0,0,0,0,0,0,0,0};
#pragma unroll
    for (int k = 0; k < 8; ++k) accum8(v0[k], w0[k], a0);
#pragma unroll
    for (int k = 0; k < 8; ++k) accum8(v1[k], w1[k], a1);

    float* row = sout + p * ROW;
    if (h == 0) { row[0] = x; row[1] = y; row[2] = z; }
#pragma unroll
    for (int k = 0; k < 8; ++k) {
        row[3 + h * 8 + k]     = a0[k] * UNSCALE;
        row[3 + D + h * 8 + k] = a1[k] * UNSCALE;
    }
    __syncthreads();

    float4*       ob = reinterpret_cast<float4*>(out + (size_t)blockIdx.x * CHUNK);
    const float4* lb = reinterpret_cast<const float4*>(sout);
    for (int i = tid; i < CHUNK / 4; i += BLOCK) {
        ob[i] = lb[i];
    }
}

// ======================= launch =======================

extern "C" void kernel_launch(void* const* d_in, const int* in_sizes, int n_in,
                              void* d_out, int out_size, void* d_ws, size_t ws_size,
                              hipStream_t stream) {
    const float* in   = (const float*)d_in[0];
    const float* emb0 = (const float*)d_in[1];
    const float* emb1 = (const float*)d_in[2];
    float*       out  = (float*)d_out;

    unsigned char* tbl = (unsigned char*)d_ws;

    if (ws_size >= DUPSZ) {
        // cell-duplicated layout: 1 line/thread/level in the gather
        cvt2_kernel<<<(TOT2 + 255) / 256, 256, 0, stream>>>(emb0, emb1, tbl);
        mhe2_kernel<<<NPTS / PPB, BLOCK, 0, stream>>>(in, tbl,
                                                      tbl + (size_t)CELLS0 * 128, out);
    } else {
        // fallback: proven Round-0 path (vertex table, 1.35 MB)
        cvt_kernel<<<(T8 + 255) / 256, 256, 0, stream>>>(emb0, emb1, tbl);
        mhe_kernel<<<NPTS / PPB, BLOCK, 0, stream>>>(in, tbl, tbl + N0, out);
    }
}

// Round 6
// 182.561 us; speedup vs baseline: 1.0756x; 1.0306x over previous
//
#include <hip/hip_runtime.h>

#define NPTS  1048576
#define BLOCK 256
#define PPB   128           // points per block (2 threads per point)
#define D     16
#define ROW   35            // 3 coords + 2*16 emb dims
#define CHUNK (PPB * ROW)   // floats per block in output (4480)

#define N0 (5 * 91 * 161 * 16)   // 1172080 bytes in fp8
#define N1 (3 * 46 * 81 * 16)    //  178848
#define T8 ((N0 + N1) / 8)       // 168866 threads for cvt

#define SCALE   4096.0f
#define UNSCALE (1.0f / 4096.0f)

typedef float vf2 __attribute__((ext_vector_type(2)));

// ---- table conversion: f32 -> fp8 e4m3 (scaled) into workspace (proven ~3µs) ----
__global__ __launch_bounds__(256) void cvt_kernel(const float* __restrict__ e0,
                                                  const float* __restrict__ e1,
                                                  unsigned char* __restrict__ dst) {
    int i = blockIdx.x * 256 + threadIdx.x;
    if (i >= T8) return;
    int e = i * 8;
    const float* src = (e < N0) ? (e0 + e) : (e1 + (e - N0));
    float4 a = *(const float4*)(src);
    float4 b = *(const float4*)(src + 4);
    int w0 = __builtin_amdgcn_cvt_pk_fp8_f32(a.x * SCALE, a.y * SCALE, 0, false);
    w0     = __builtin_amdgcn_cvt_pk_fp8_f32(a.z * SCALE, a.w * SCALE, w0, true);
    int w1 = __builtin_amdgcn_cvt_pk_fp8_f32(b.x * SCALE, b.y * SCALE, 0, false);
    w1     = __builtin_amdgcn_cvt_pk_fp8_f32(b.z * SCALE, b.w * SCALE, w1, true);
    uint2 packed;
    packed.x = (unsigned int)w0;
    packed.y = (unsigned int)w1;
    *reinterpret_cast<uint2*>(dst + e) = packed;
}

// w-axis: contiguous cell pair {ic, ic+1} + quirk-exact weights (proven bit-identical
// in R4/R5): reference's +1 corner = floorf(c+1.0f) then clip. Freak points fold the
// -eps weight onto ic+1 (error ~1e-11); c==G-1 edge gives {0, w0+w1} exactly.
__device__ __forceinline__ void axisw(float c, float Gm1f, float Gm2f,
                                      int& ic, float& wA, float& wB) {
    float f0 = floorf(c);
    float f1 = fminf(floorf(c + 1.f), Gm1f);
    float w0 = 1.f - fabsf(f0 - c);
    float w1 = 1.f - fabsf(f1 - c);
    float fc = fminf(f0, Gm2f);
    ic = (int)fc;
    bool same = (f0 == fc);
    wA = same ? w0 : 0.f;
    wB = same ? w1 : (w0 + w1);
}

// Per level: 4 (t,u) base byte-offsets (quirk-exact separate indices: freak points
// can make the +1 index land at +2 — we honor it) + wtu products + w-pair weights
// pre-scaled by UNSCALE.
template <int GT, int GU, int GW>
__device__ __forceinline__ void prep_lean(float x, float y, float z, int h,
                                          int* __restrict__ cb,     // [4] byte offsets
                                          float* __restrict__ wtu,  // [4]
                                          float& wwA, float& wwB) {
    float ct = x * (float)(GT - 1);
    float cu = y * (float)(GU - 1);
    float cw = z * (float)(GW - 1);

    // t,u: both corners as full indices (no lower clamp needed: c >= 0 always;
    // upper fmin needed: floorf(c+1) can round up to G at fp ties)
    float t0 = floorf(ct), u0 = floorf(cu);
    float t1 = fminf(floorf(ct + 1.f), (float)(GT - 1));
    float u1 = fminf(floorf(cu + 1.f), (float)(GU - 1));
    float wt0 = 1.f - fabsf(t0 - ct), wt1 = 1.f - fabsf(t1 - ct);
    float wu0 = 1.f - fabsf(u0 - cu), wu1 = 1.f - fabsf(u1 - cu);

    int iw;
    axisw(cw, (float)(GW - 1), (float)(GW - 2), iw, wwA, wwB);
    wwA *= UNSCALE;                      // fold final unscale into w-axis weights
    wwB *= UNSCALE;

    int rT0 = (int)t0 * GU, rT1 = (int)t1 * GU;
    int iu0 = (int)u0,      iu1 = (int)u1;
    int colw = iw * D + h * 8;           // byte offset of my half within the w0 cell
    const int GWD = GW * D;

    cb[0] = (rT0 + iu0) * GWD + colw;
    cb[1] = (rT0 + iu1) * GWD + colw;
    cb[2] = (rT1 + iu0) * GWD + colw;
    cb[3] = (rT1 + iu1) * GWD + colw;
    wtu[0] = wt0 * wu0;
    wtu[1] = wt0 * wu1;
    wtu[2] = wt1 * wu0;
    wtu[3] = wt1 * wu1;
}

// accumulate 8 fp8 channels (one uint2) with weight w into 4 packed-f32 accs
// (cvt_pk returns a pair; += w2*pair contracts to v_pk_fma_f32)
__device__ __forceinline__ void accum8p(uint2 v, float w, vf2* __restrict__ acc) {
    vf2 w2 = {w, w};
    acc[0] += w2 * __builtin_amdgcn_cvt_pk_f32_fp8((int)v.x, false);
    acc[1] += w2 * __builtin_amdgcn_cvt_pk_f32_fp8((int)v.x, true);
    acc[2] += w2 * __builtin_amdgcn_cvt_pk_f32_fp8((int)v.y, false);
    acc[3] += w2 * __builtin_amdgcn_cvt_pk_f32_fp8((int)v.y, true);
}

__global__ __launch_bounds__(BLOCK) void mhe_kernel(
    const float* __restrict__ in,            // [N,3]
    const unsigned char* __restrict__ e0,    // [5,91,161,16] fp8 e4m3 (x4096)
    const unsigned char* __restrict__ e1,    // [3,46,81,16]  fp8 e4m3 (x4096)
    float* __restrict__ out)                 // [N,35]
{
    __shared__ float sin_[PPB * 3];   // 1536 B
    __shared__ float sout[CHUNK];     // 17920 B

    const int tid  = threadIdx.x;
    const int base = blockIdx.x * PPB;

    // coalesced input staging: 384 floats as 192 float2
    if (tid < PPB * 3 / 2) {
        reinterpret_cast<float2*>(sin_)[tid] =
            reinterpret_cast<const float2*>(in + (size_t)base * 3)[tid];
    }
    __syncthreads();

    const int p = tid >> 1;     // point within block
    const int h = tid & 1;      // channel half (8 channels)

    float x = sin_[p * 3 + 0];
    float y = sin_[p * 3 + 1];
    float z = sin_[p * 3 + 2];

    int   cb0[4], cb1[4];
    float wtu0[4], wtu1[4];
    float wwA0, wwB0, wwA1, wwB1;
    prep_lean<5, 91, 161>(x, y, z, h, cb0, wtu0, wwA0, wwB0);
    prep_lean<3, 46, 81>(x, y, z, h, cb1, wtu1, wwA1, wwB1);

    // 16 independent 8B gathers, 8 computed bases + imm offset 16 for the +w cell
    uint2 vA0[4], vB0[4], vA1[4], vB1[4];
#pragma unroll
    for (int k = 0; k < 4; ++k) {
        vA0[k] = *reinterpret_cast<const uint2*>(e0 + cb0[k]);
        vB0[k] = *reinterpret_cast<const uint2*>(e0 + cb0[k] + 16);
    }
#pragma unroll
    for (int k = 0; k < 4; ++k) {
        vA1[k] = *reinterpret_cast<const uint2*>(e1 + cb1[k]);
        vB1[k] = *reinterpret_cast<const uint2*>(e1 + cb1[k] + 16);
    }

    vf2 a0[4] = {{0,0},{0,0},{0,0},{0,0}};
    vf2 a1[4] = {{0,0},{0,0},{0,0},{0,0}};
#pragma unroll
    for (int k = 0; k < 4; ++k) {
        accum8p(vA0[k], wtu0[k] * wwA0, a0);
        accum8p(vB0[k], wtu0[k] * wwB0, a0);
    }
#pragma unroll
    for (int k = 0; k < 4; ++k) {
        accum8p(vA1[k], wtu1[k] * wwA1, a1);
        accum8p(vB1[k], wtu1[k] * wwB1, a1);
    }

    float* row = sout + p * ROW;
    if (h == 0) { row[0] = x; row[1] = y; row[2] = z; }
#pragma unroll
    for (int j = 0; j < 4; ++j) {
        row[3 + h * 8 + 2 * j]         = a0[j].x;
        row[3 + h * 8 + 2 * j + 1]     = a0[j].y;
        row[3 + D + h * 8 + 2 * j]     = a1[j].x;
        row[3 + D + h * 8 + 2 * j + 1] = a1[j].y;
    }
    __syncthreads();

    // coalesced flush: 1120 float4 per block
    float4*       ob = reinterpret_cast<float4*>(out + (size_t)blockIdx.x * CHUNK);
    const float4* lb = reinterpret_cast<const float4*>(sout);
    for (int i = tid; i < CHUNK / 4; i += BLOCK) {
        ob[i] = lb[i];
    }
}

extern "C" void kernel_launch(void* const* d_in, const int* in_sizes, int n_in,
                              void* d_out, int out_size, void* d_ws, size_t ws_size,
                              hipStream_t stream) {
    const float* in   = (const float*)d_in[0];
    const float* emb0 = (const float*)d_in[1];
    const float* emb1 = (const float*)d_in[2];
    float*       out  = (float*)d_out;

    unsigned char* tbl = (unsigned char*)d_ws;   // e0 at [0, N0), e1 at [N0, N0+N1)

    cvt_kernel<<<(T8 + 255) / 256, 256, 0, stream>>>(emb0, emb1, tbl);
    mhe_kernel<<<NPTS / PPB, BLOCK, 0, stream>>>(in, tbl, tbl + N0, out);
}